// Round 9
// baseline (712.571 us; speedup 1.0000x reference)
//
#include <hip/hip_runtime.h>
#include <hip/hip_bf16.h>

typedef __attribute__((ext_vector_type(8))) _Float16 f16x8;
typedef __attribute__((ext_vector_type(8))) short short8;
typedef __attribute__((ext_vector_type(4))) short short4v;
typedef __attribute__((ext_vector_type(4))) float f32x4;

#define LDP 72  // LDS row stride (shorts) for GEMM tiles

__device__ __forceinline__ short f2h(float f) {
  union { _Float16 h; short s; } u; u.h = (_Float16)f; return u.s;
}
__device__ __forceinline__ float h2f(short s) {
  union { short s; _Float16 h; } u; u.s = s; return (float)u.h;
}

// ---------------- weight transpose + f32->f16 ----------------
__global__ __launch_bounds__(256) void k_tw(const float* __restrict__ W,
                                            const float* __restrict__ Wo,
                                            short* __restrict__ WT,
                                            short* __restrict__ WoT) {
  int idx = blockIdx.x * 256 + threadIdx.x;
  if (idx < 3 * 512 * 128) {
    int l = idx >> 16, rem = idx & 65535;
    int c = rem >> 7, k = rem & 127;
    int h = c >> 7, o = c & 127;
    WT[idx] = f2h(W[(((l * 4 + h) * 128 + k) << 7) + o]);
  } else {
    int j = idx - 3 * 512 * 128;
    int l = j >> 16, rem = j & 65535;
    int d = rem >> 9, c = rem & 511;
    WoT[j] = f2h(Wo[((l * 512 + c) << 7) + d]);
  }
}

// ---------------- input projection ----------------
__global__ __launch_bounds__(256) void k_inproj(const float* __restrict__ nf,
                                                const float* __restrict__ Wp,
                                                const float* __restrict__ bp,
                                                short* __restrict__ xh) {
  int idx = blockIdx.x * 256 + threadIdx.x;
  int bn = idx >> 7, d = idx & 127;
  float acc = bp[d];
  const float* nr = nf + bn * 7;
#pragma unroll
  for (int i = 0; i < 7; ++i) acc += nr[i] * Wp[(i << 7) + d];
  xh[idx] = f2h(acc);
}

// ---------------- head projection (row layout) + fused s1/s2 ----------------
// hrow[bh][n][d] = x @ W[h]; s1/s2[bh][n] = h.a1 / h.a2 (f32 exact).
// MFMA operands swapped (A = weight rows, B = token rows) so C rows = d
// (4 consecutive per lane -> short4v stores into row-major hrow).
__global__ __launch_bounds__(256) void k_gemm_h(const short* __restrict__ xh,
                                                const short* __restrict__ WT,
                                                short* __restrict__ hrow,
                                                const float* __restrict__ a1,
                                                const float* __restrict__ a2,
                                                float* __restrict__ s1g,
                                                float* __restrict__ s2g) {
  __shared__ __align__(16) short As[128 * LDP];
  __shared__ __align__(16) short Bs[128 * LDP];
  __shared__ float sred[2][2][128];
  const int t = threadIdx.x;
  const int bn0 = blockIdx.x << 7;
  const int head = blockIdx.y;
  const int c0 = head << 7;
  const int w = t >> 6, lane = t & 63, lr = lane & 15, lq = lane >> 4;
  const int wr = w >> 1, wc = w & 1;
  f32x4 acc[4][4] = {};
  for (int k0 = 0; k0 < 128; k0 += 64) {
    const int row = t >> 1, half = (t & 1) << 5;
    {
      const short* sa = xh + ((bn0 + row) << 7) + k0 + half;
      short* da = As + row * LDP + half;
      *(short8*)(da) = *(const short8*)(sa);
      *(short8*)(da + 8) = *(const short8*)(sa + 8);
      *(short8*)(da + 16) = *(const short8*)(sa + 16);
      *(short8*)(da + 24) = *(const short8*)(sa + 24);
      const short* sb = WT + ((c0 + row) << 7) + k0 + half;
      short* db = Bs + row * LDP + half;
      *(short8*)(db) = *(const short8*)(sb);
      *(short8*)(db + 8) = *(const short8*)(sb + 8);
      *(short8*)(db + 16) = *(const short8*)(sb + 16);
      *(short8*)(db + 24) = *(const short8*)(sb + 24);
    }
    __syncthreads();
#pragma unroll
    for (int kk = 0; kk < 2; ++kk) {
      f16x8 aW[4], bX[4];
#pragma unroll
      for (int m = 0; m < 4; ++m)
        aW[m] = *(const f16x8*)(Bs + (wr * 64 + m * 16 + lr) * LDP + (kk << 5) + (lq << 3));
#pragma unroll
      for (int n = 0; n < 4; ++n)
        bX[n] = *(const f16x8*)(As + (wc * 64 + n * 16 + lr) * LDP + (kk << 5) + (lq << 3));
#pragma unroll
      for (int m = 0; m < 4; ++m)
#pragma unroll
        for (int n = 0; n < 4; ++n)
          acc[m][n] = __builtin_amdgcn_mfma_f32_16x16x32_f16(aW[m], bX[n], acc[m][n], 0, 0, 0);
    }
    __syncthreads();
  }
  const int b = bn0 >> 10;
  const int nb = bn0 & 1023;
  const int bh = (b << 2) + head;
  // fused s1/s2: per-token dot with a1/a2; o(m,r) = wr*64+m*16+lq*4+r
  f32x4 av1[4], av2[4];
#pragma unroll
  for (int m = 0; m < 4; ++m) {
    av1[m] = *(const f32x4*)&a1[(head << 7) + wr * 64 + m * 16 + (lq << 2)];
    av2[m] = *(const f32x4*)&a2[(head << 7) + wr * 64 + m * 16 + (lq << 2)];
  }
#pragma unroll
  for (int nn = 0; nn < 4; ++nn) {
    float v1 = 0.f, v2 = 0.f;
#pragma unroll
    for (int m = 0; m < 4; ++m)
#pragma unroll
      for (int r = 0; r < 4; ++r) {
        v1 += acc[m][nn][r] * av1[m][r];
        v2 += acc[m][nn][r] * av2[m][r];
      }
    v1 += __shfl_xor(v1, 16); v1 += __shfl_xor(v1, 32);
    v2 += __shfl_xor(v2, 16); v2 += __shfl_xor(v2, 32);
    if (lq == 0) {
      int tok = wc * 64 + nn * 16 + lr;
      sred[wr][0][tok] = v1;
      sred[wr][1][tok] = v2;
    }
  }
#pragma unroll
  for (int m = 0; m < 4; ++m) {
    int o0 = wr * 64 + m * 16 + (lq << 2);
#pragma unroll
    for (int nn = 0; nn < 4; ++nn) {
      int tok = wc * 64 + nn * 16 + lr;
      short4v v;
      v[0] = f2h(acc[m][nn][0]); v[1] = f2h(acc[m][nn][1]);
      v[2] = f2h(acc[m][nn][2]); v[3] = f2h(acc[m][nn][3]);
      *(short4v*)(hrow + (((long)(bh << 10) + nb + tok) << 7) + o0) = v;
    }
  }
  __syncthreads();
  if (t < 128)
    s1g[(bh << 10) + nb + t] = sred[0][0][t] + sred[1][0][t];
  else
    s2g[(bh << 10) + nb + (t - 128)] = sred[0][1][t - 128] + sred[1][1][t - 128];
}

// ---------------- rank + per-row threshold + sorted E/F scatter ----------------
// grid (64 bh, 4 seg), 256 thr. Each thread owns one index j (== row i).
// rank_j = #{j': s2_j' > s2_j or (== and j'<j)}  -> desc-sort permutation.
// k_i    = #{j : s2_j > -s1_i}  (strict).
__global__ __launch_bounds__(256) void k_rank(const float* __restrict__ s1g,
                                              const float* __restrict__ s2g,
                                              float* __restrict__ sE,
                                              float* __restrict__ sF,
                                              int* __restrict__ sidx,
                                              int* __restrict__ ki,
                                              float* __restrict__ rowA,
                                              float* __restrict__ rowB,
                                              float* __restrict__ rowPd) {
  __shared__ float s2s[1024];
  __shared__ float red[4];
  const int bh = blockIdx.x, seg = blockIdx.y, t = threadIdx.x;
  f32x4 v4 = *(const f32x4*)&s2g[(bh << 10) + (t << 2)];
  *(f32x4*)&s2s[t << 2] = v4;
  __syncthreads();
  float mx = fmaxf(fmaxf(v4[0], v4[1]), fmaxf(v4[2], v4[3]));
#pragma unroll
  for (int off = 1; off < 64; off <<= 1) mx = fmaxf(mx, __shfl_xor(mx, off));
  if ((t & 63) == 0) red[t >> 6] = mx;
  __syncthreads();
  const float smax = fmaxf(fmaxf(red[0], red[1]), fmaxf(red[2], red[3]));

  const int j = (seg << 8) + t;
  const float s2j = s2s[j];
  const float s1v = s1g[(bh << 10) + j];
  const float thr = -s1v;
  int rank = 0, k = 0;
#pragma unroll 4
  for (int p4 = 0; p4 < 256; ++p4) {
    f32x4 v = *(const f32x4*)&s2s[p4 << 2];
#pragma unroll
    for (int q = 0; q < 4; ++q) {
      int p = (p4 << 2) + q;
      rank += (v[q] > s2j) || (v[q] == s2j && p < j);
      k += (v[q] > thr);
    }
  }
  const float E = __expf(s2j - smax);
  const float F = __expf(0.2f * (s2j - smax));
  const int o = (bh << 10) + rank;
  sE[o] = E; sF[o] = F; sidx[o] = j;

  float x = s1v + smax;
  float mi = fmaxf(x, 0.2f * x);  // >= row max of lrelu scores (monotone)
  float A = __expf(x - mi);
  float Bv = __expf(0.2f * x - mi);
  float xii = s1v + s2j;
  float Pd = (xii > 0.f) ? A * E : Bv * F;  // diagonal term to subtract
  const int ro = (bh << 10) + j;
  rowA[ro] = A; rowB[ro] = Bv; rowPd[ro] = Pd; ki[ro] = k;
}

// ---------------- chunk sums: PEb/PFb[bh][c] = sum over chunk c of E/F * h ---
// grid (64 bh, 8 cg), 256 thr (128 d x 2 chunk-halves)
__global__ __launch_bounds__(256) void k_scan_a(const float* __restrict__ sE,
                                                const float* __restrict__ sF,
                                                const int* __restrict__ sidx,
                                                const short* __restrict__ hrow,
                                                float* __restrict__ PEb,
                                                float* __restrict__ PFb) {
  const int bh = blockIdx.x, cg = blockIdx.y, t = threadIdx.x;
  const int d = t & 127, half = t >> 7;
#pragma unroll
  for (int cc = 0; cc < 4; ++cc) {
    const int c = (cg << 3) + (cc << 1) + half;
    float aE = 0.f, aF = 0.f;
#pragma unroll
    for (int p16 = 0; p16 < 16; ++p16) {
      const int p = (bh << 10) + (c << 4) + p16;
      float e = sE[p], f = sF[p];
      int jj = sidx[p];
      float hv = h2f(hrow[(((bh << 10) + jj) << 7) + d]);
      aE += e * hv;
      aF += f * hv;
    }
    PEb[(bh * 65 + c) * 128 + d] = aE;
    PFb[(bh * 65 + c) * 128 + d] = aF;
  }
}

// ---------------- exclusive scan of chunk sums (in place) + scalar bounds ----
// grid 64 bh, 256 thr
__global__ __launch_bounds__(256) void k_scan_b(float* __restrict__ PEb,
                                                float* __restrict__ PFb,
                                                const float* __restrict__ sE,
                                                const float* __restrict__ sF,
                                                float* __restrict__ cEb,
                                                float* __restrict__ cFb) {
  __shared__ float ce[64], cf[64];
  const int bh = blockIdx.x, t = threadIdx.x;
  if (t < 128) {
    const int d = t;
    float run = 0.f;
#pragma unroll 4
    for (int c = 0; c < 64; ++c) {
      int idx = (bh * 65 + c) * 128 + d;
      float tmp = PEb[idx];
      PEb[idx] = run;
      run += tmp;
    }
    PEb[(bh * 65 + 64) * 128 + d] = run;
  } else {
    const int d = t - 128;
    float run = 0.f;
#pragma unroll 4
    for (int c = 0; c < 64; ++c) {
      int idx = (bh * 65 + c) * 128 + d;
      float tmp = PFb[idx];
      PFb[idx] = run;
      run += tmp;
    }
    PFb[(bh * 65 + 64) * 128 + d] = run;
  }
  if (t < 64) {
    float se = 0.f, sf = 0.f;
#pragma unroll
    for (int p16 = 0; p16 < 16; ++p16) {
      se += sE[(bh << 10) + (t << 4) + p16];
      sf += sF[(bh << 10) + (t << 4) + p16];
    }
    ce[t] = se; cf[t] = sf;
  }
  __syncthreads();
  if (t == 0) {
    float rE = 0.f, rF = 0.f;
    for (int c = 0; c < 64; ++c) {
      float tE = ce[c], tF = cf[c];
      cEb[bh * 65 + c] = rE;
      cFb[bh * 65 + c] = rF;
      rE += tE; rF += tF;
    }
    cEb[bh * 65 + 64] = rE;
    cFb[bh * 65 + 64] = rF;
  }
}

// ---------------- per-row output: prefix lookup + 16-wide chunk correction ---
// grid (64 bh, 8 ig), 256 thr (128 d x 2 rows in flight)
__global__ __launch_bounds__(256) void k_row(const int* __restrict__ ki,
                                             const float* __restrict__ rowA,
                                             const float* __restrict__ rowB,
                                             const float* __restrict__ rowPd,
                                             const float* __restrict__ sE,
                                             const float* __restrict__ sF,
                                             const int* __restrict__ sidx,
                                             const short* __restrict__ hrow,
                                             const float* __restrict__ PEb,
                                             const float* __restrict__ PFb,
                                             const float* __restrict__ cEb,
                                             const float* __restrict__ cFb,
                                             short* __restrict__ attn) {
  const int bh = blockIdx.x, ig = blockIdx.y, t = threadIdx.x;
  const int d = t & 127, rh = t >> 7;
  const int b = bh >> 2, head = bh & 3;
  const float totFh = PFb[(bh * 65 + 64) * 128 + d];
  const float totF = cFb[bh * 65 + 64];
#pragma unroll 1
  for (int rr = 0; rr < 64; ++rr) {
    const int i = (ig << 7) + (rr << 1) + rh;
    const int ro = (bh << 10) + i;
    int k = ki[ro];
    int c = k >> 4; if (c > 63) c = 63;
    const int kin = k - (c << 4);
    const float A = rowA[ro], Bv = rowB[ro], Pd = rowPd[ro];
    float num = A * PEb[(bh * 65 + c) * 128 + d] +
                Bv * (totFh - PFb[(bh * 65 + c + 1) * 128 + d]);
    float den = A * cEb[bh * 65 + c] + Bv * (totF - cFb[bh * 65 + c + 1]);
#pragma unroll
    for (int p16 = 0; p16 < 16; ++p16) {
      const int p = (bh << 10) + (c << 4) + p16;
      float e = sE[p], f = sF[p];
      int jj = sidx[p];
      float w = (p16 < kin) ? A * e : Bv * f;
      float hv = h2f(hrow[(((bh << 10) + jj) << 7) + d]);
      num += w * hv;
      den += w;
    }
    float hvi = h2f(hrow[(((bh << 10) + i) << 7) + d]);
    num -= Pd * hvi;
    den -= Pd;
    attn[(((long)((b << 10) + i)) << 9) + (head << 7) + d] = f2h(num / den);
  }
}

// ---------------- out-proj + bias (+residual from xh) + LN (+relu) ----------
// 32-row blocks, grid 512 (2 blocks/CU). Wave owns 16 rows x 64 cols; LN via
// cross-wave LDS partial-sum exchange.
template <int HAS_RES, int DO_RELU, int WRITE_OUT>
__global__ __launch_bounds__(256) void k_outproj(const short* __restrict__ attn,
                                                 const short* __restrict__ WoT,
                                                 const float* __restrict__ bo,
                                                 const float* __restrict__ gamma,
                                                 const float* __restrict__ beta,
                                                 short* __restrict__ xh,
                                                 float* __restrict__ outp) {
  __shared__ __align__(16) short As[32 * LDP];
  __shared__ __align__(16) short Bs[128 * LDP];
  __shared__ float sredS[2][32], sredQ[2][32];
  const int t = threadIdx.x;
  const int bn0 = blockIdx.x << 5;
  const int w = t >> 6, lane = t & 63, lr = lane & 15, lq = lane >> 4;
  const int wm = w & 1, wn = w >> 1;
  f32x4 acc[4] = {};
  const int rowA_ = t >> 3, chA = (t & 7) << 3;
  const int rowB_ = t >> 1, chB = (t & 1) << 5;
  for (int k0 = 0; k0 < 512; k0 += 64) {
    {
      const short* sa = attn + ((long)(bn0 + rowA_) << 9) + k0 + chA;
      *(short8*)(As + rowA_ * LDP + chA) = *(const short8*)(sa);
      const short* sb = WoT + (rowB_ << 9) + k0 + chB;
      short* db = Bs + rowB_ * LDP + chB;
      *(short8*)(db) = *(const short8*)(sb);
      *(short8*)(db + 8) = *(const short8*)(sb + 8);
      *(short8*)(db + 16) = *(const short8*)(sb + 16);
      *(short8*)(db + 24) = *(const short8*)(sb + 24);
    }
    __syncthreads();
#pragma unroll
    for (int kk = 0; kk < 2; ++kk) {
      f16x8 a = *(const f16x8*)(As + ((wm << 4) + lr) * LDP + (kk << 5) + (lq << 3));
#pragma unroll
      for (int nn = 0; nn < 4; ++nn) {
        f16x8 b = *(const f16x8*)(Bs + ((wn << 6) + (nn << 4) + lr) * LDP + (kk << 5) + (lq << 3));
        acc[nn] = __builtin_amdgcn_mfma_f32_16x16x32_f16(a, b, acc[nn], 0, 0, 0);
      }
    }
    __syncthreads();
  }
  float v[4][4], gam[4], bet[4];
#pragma unroll
  for (int nn = 0; nn < 4; ++nn) {
    int d = (wn << 6) + (nn << 4) + lr;
    float bv = bo[d];
    gam[nn] = gamma[d];
    bet[nn] = beta[d];
#pragma unroll
    for (int r = 0; r < 4; ++r) {
      float x = acc[nn][r] + bv;
      if (HAS_RES) x += h2f(xh[((bn0 + (wm << 4) + (lq << 2) + r) << 7) + d]);
      v[nn][r] = x;
    }
  }
#pragma unroll
  for (int r = 0; r < 4; ++r) {
    float s = 0.f, q = 0.f;
#pragma unroll
    for (int nn = 0; nn < 4; ++nn) { s += v[nn][r]; q += v[nn][r] * v[nn][r]; }
#pragma unroll
    for (int mk = 1; mk < 16; mk <<= 1) { s += __shfl_xor(s, mk); q += __shfl_xor(q, mk); }
    if (lr == 0) {
      int row = (wm << 4) + (lq << 2) + r;
      sredS[wn][row] = s;
      sredQ[wn][row] = q;
    }
  }
  __syncthreads();
#pragma unroll
  for (int r = 0; r < 4; ++r) {
    int rloc = (wm << 4) + (lq << 2) + r;
    float S = sredS[0][rloc] + sredS[1][rloc];
    float Q = sredQ[0][rloc] + sredQ[1][rloc];
    float mean = S * 0.0078125f;
    float var = Q * 0.0078125f - mean * mean;
    float rstd = rsqrtf(var + 1e-5f);
    int row = bn0 + rloc;
#pragma unroll
    for (int nn = 0; nn < 4; ++nn) {
      int d = (wn << 6) + (nn << 4) + lr;
      float o = (v[nn][r] - mean) * rstd * gam[nn] + bet[nn];
      if (DO_RELU) o = fmaxf(o, 0.f);
      if (WRITE_OUT) outp[(row << 7) + d] = o;
      else xh[(row << 7) + d] = f2h(o);
    }
  }
}

extern "C" void kernel_launch(void* const* d_in, const int* in_sizes, int n_in,
                              void* d_out, int out_size, void* d_ws, size_t ws_size,
                              hipStream_t stream) {
  const float* nf = (const float*)d_in[0];
  const float* Wp = (const float*)d_in[1];
  const float* bp = (const float*)d_in[2];
  const float* W = (const float*)d_in[3];
  const float* a1 = (const float*)d_in[4];
  const float* a2 = (const float*)d_in[5];
  const float* Wo = (const float*)d_in[6];
  const float* bo = (const float*)d_in[7];
  const float* gamma = (const float*)d_in[8];
  const float* beta = (const float*)d_in[9];
  float* outp = (float*)d_out;

  char* ws = (char*)d_ws;
  short* xh = (short*)(ws);                        // 4 MB  [16384][128] f16
  short* hrow = (short*)(ws + (4ll << 20));        // 16 MB [64][1024][128] f16
  short* attn = (short*)(ws + (20ll << 20));       // 16 MB [16384][512] f16
  char* aux = ws + (36ll << 20);
  float* s1g = (float*)(aux);                      // 256 KB
  float* s2g = (float*)(aux + (256ll << 10));      // 256 KB
  float* sE = (float*)(aux + (512ll << 10));       // 256 KB sorted E
  float* sF = (float*)(aux + (768ll << 10));       // 256 KB sorted F
  int* sidx = (int*)(aux + (1024ll << 10));        // 256 KB sorted->orig idx
  int* ki = (int*)(aux + (1280ll << 10));          // 256 KB per-row threshold
  float* rowA = (float*)(aux + (1536ll << 10));    // 256 KB
  float* rowB = (float*)(aux + (1792ll << 10));    // 256 KB
  float* rowPd = (float*)(aux + (2048ll << 10));   // 256 KB
  float* cEb = (float*)(aux + (2304ll << 10));     // 17 KB (64*65 f32)
  float* cFb = (float*)(aux + (2368ll << 10));     // 17 KB
  float* PEb = (float*)(aux + (2432ll << 10));     // 2.08 MB [64][65][128]
  float* PFb = (float*)(aux + (4608ll << 10));     // 2.08 MB
  short* WT = (short*)(aux + (6784ll << 10));      // 384 KB
  short* WoT = (short*)(aux + (6784ll << 10) + 393216);  // 384 KB

  k_tw<<<1536, 256, 0, stream>>>(W, Wo, WT, WoT);
  k_inproj<<<8192, 256, 0, stream>>>(nf, Wp, bp, xh);
  for (int l = 0; l < 3; ++l) {
    k_gemm_h<<<dim3(128, 4), 256, 0, stream>>>(xh, WT + l * 65536, hrow,
                                               a1 + l * 512, a2 + l * 512, s1g, s2g);
    k_rank<<<dim3(64, 4), 256, 0, stream>>>(s1g, s2g, sE, sF, sidx, ki,
                                            rowA, rowB, rowPd);
    k_scan_a<<<dim3(64, 8), 256, 0, stream>>>(sE, sF, sidx, hrow, PEb, PFb);
    k_scan_b<<<64, 256, 0, stream>>>(PEb, PFb, sE, sF, cEb, cFb);
    k_row<<<dim3(64, 8), 256, 0, stream>>>(ki, rowA, rowB, rowPd, sE, sF, sidx,
                                           hrow, PEb, PFb, cEb, cFb, attn);
    if (l == 0)
      k_outproj<0, 1, 0><<<512, 256, 0, stream>>>(attn, WoT + l * 65536, bo + l * 128,
                                                  gamma + l * 128, beta + l * 128, xh, outp);
    else if (l == 1)
      k_outproj<1, 1, 0><<<512, 256, 0, stream>>>(attn, WoT + l * 65536, bo + l * 128,
                                                  gamma + l * 128, beta + l * 128, xh, outp);
    else
      k_outproj<1, 0, 1><<<512, 256, 0, stream>>>(attn, WoT + l * 65536, bo + l * 128,
                                                  gamma + l * 128, beta + l * 128, xh, outp);
  }
}

// Round 10
// 653.740 us; speedup vs baseline: 1.0900x; 1.0900x over previous
//
#include <hip/hip_runtime.h>
#include <hip/hip_bf16.h>

typedef __attribute__((ext_vector_type(8))) _Float16 f16x8;
typedef __attribute__((ext_vector_type(8))) short short8;
typedef __attribute__((ext_vector_type(4))) short short4v;
typedef __attribute__((ext_vector_type(4))) float f32x4;
typedef __attribute__((ext_vector_type(4))) int int4v;

#define LDP 72  // LDS row stride (shorts) for GEMM tiles

__device__ __forceinline__ short f2h(float f) {
  union { _Float16 h; short s; } u; u.h = (_Float16)f; return u.s;
}
__device__ __forceinline__ float h2f(short s) {
  union { short s; _Float16 h; } u; u.s = s; return (float)u.h;
}

// ---------------- weight transpose + f32->f16 ----------------
__global__ __launch_bounds__(256) void k_tw(const float* __restrict__ W,
                                            const float* __restrict__ Wo,
                                            short* __restrict__ WT,
                                            short* __restrict__ WoT) {
  int idx = blockIdx.x * 256 + threadIdx.x;
  if (idx < 3 * 512 * 128) {
    int l = idx >> 16, rem = idx & 65535;
    int c = rem >> 7, k = rem & 127;
    int h = c >> 7, o = c & 127;
    WT[idx] = f2h(W[(((l * 4 + h) * 128 + k) << 7) + o]);
  } else {
    int j = idx - 3 * 512 * 128;
    int l = j >> 16, rem = j & 65535;
    int d = rem >> 9, c = rem & 511;
    WoT[j] = f2h(Wo[((l * 512 + c) << 7) + d]);
  }
}

// ---------------- input projection ----------------
__global__ __launch_bounds__(256) void k_inproj(const float* __restrict__ nf,
                                                const float* __restrict__ Wp,
                                                const float* __restrict__ bp,
                                                short* __restrict__ xh) {
  int idx = blockIdx.x * 256 + threadIdx.x;
  int bn = idx >> 7, d = idx & 127;
  float acc = bp[d];
  const float* nr = nf + bn * 7;
#pragma unroll
  for (int i = 0; i < 7; ++i) acc += nr[i] * Wp[(i << 7) + d];
  xh[idx] = f2h(acc);
}

// ---------------- head projection (row layout) + fused s1/s2 ----------------
__global__ __launch_bounds__(256) void k_gemm_h(const short* __restrict__ xh,
                                                const short* __restrict__ WT,
                                                short* __restrict__ hrow,
                                                const float* __restrict__ a1,
                                                const float* __restrict__ a2,
                                                float* __restrict__ s1g,
                                                float* __restrict__ s2g) {
  __shared__ __align__(16) short As[128 * LDP];
  __shared__ __align__(16) short Bs[128 * LDP];
  __shared__ float sred[2][2][128];
  const int t = threadIdx.x;
  const int bn0 = blockIdx.x << 7;
  const int head = blockIdx.y;
  const int c0 = head << 7;
  const int w = t >> 6, lane = t & 63, lr = lane & 15, lq = lane >> 4;
  const int wr = w >> 1, wc = w & 1;
  f32x4 acc[4][4] = {};
  for (int k0 = 0; k0 < 128; k0 += 64) {
    const int row = t >> 1, half = (t & 1) << 5;
    {
      const short* sa = xh + ((bn0 + row) << 7) + k0 + half;
      short* da = As + row * LDP + half;
      *(short8*)(da) = *(const short8*)(sa);
      *(short8*)(da + 8) = *(const short8*)(sa + 8);
      *(short8*)(da + 16) = *(const short8*)(sa + 16);
      *(short8*)(da + 24) = *(const short8*)(sa + 24);
      const short* sb = WT + ((c0 + row) << 7) + k0 + half;
      short* db = Bs + row * LDP + half;
      *(short8*)(db) = *(const short8*)(sb);
      *(short8*)(db + 8) = *(const short8*)(sb + 8);
      *(short8*)(db + 16) = *(const short8*)(sb + 16);
      *(short8*)(db + 24) = *(const short8*)(sb + 24);
    }
    __syncthreads();
#pragma unroll
    for (int kk = 0; kk < 2; ++kk) {
      f16x8 aW[4], bX[4];
#pragma unroll
      for (int m = 0; m < 4; ++m)
        aW[m] = *(const f16x8*)(Bs + (wr * 64 + m * 16 + lr) * LDP + (kk << 5) + (lq << 3));
#pragma unroll
      for (int n = 0; n < 4; ++n)
        bX[n] = *(const f16x8*)(As + (wc * 64 + n * 16 + lr) * LDP + (kk << 5) + (lq << 3));
#pragma unroll
      for (int m = 0; m < 4; ++m)
#pragma unroll
        for (int n = 0; n < 4; ++n)
          acc[m][n] = __builtin_amdgcn_mfma_f32_16x16x32_f16(aW[m], bX[n], acc[m][n], 0, 0, 0);
    }
    __syncthreads();
  }
  const int b = bn0 >> 10;
  const int nb = bn0 & 1023;
  const int bh = (b << 2) + head;
  f32x4 av1[4], av2[4];
#pragma unroll
  for (int m = 0; m < 4; ++m) {
    av1[m] = *(const f32x4*)&a1[(head << 7) + wr * 64 + m * 16 + (lq << 2)];
    av2[m] = *(const f32x4*)&a2[(head << 7) + wr * 64 + m * 16 + (lq << 2)];
  }
#pragma unroll
  for (int nn = 0; nn < 4; ++nn) {
    float v1 = 0.f, v2 = 0.f;
#pragma unroll
    for (int m = 0; m < 4; ++m)
#pragma unroll
      for (int r = 0; r < 4; ++r) {
        v1 += acc[m][nn][r] * av1[m][r];
        v2 += acc[m][nn][r] * av2[m][r];
      }
    v1 += __shfl_xor(v1, 16); v1 += __shfl_xor(v1, 32);
    v2 += __shfl_xor(v2, 16); v2 += __shfl_xor(v2, 32);
    if (lq == 0) {
      int tok = wc * 64 + nn * 16 + lr;
      sred[wr][0][tok] = v1;
      sred[wr][1][tok] = v2;
    }
  }
#pragma unroll
  for (int m = 0; m < 4; ++m) {
    int o0 = wr * 64 + m * 16 + (lq << 2);
#pragma unroll
    for (int nn = 0; nn < 4; ++nn) {
      int tok = wc * 64 + nn * 16 + lr;
      short4v v;
      v[0] = f2h(acc[m][nn][0]); v[1] = f2h(acc[m][nn][1]);
      v[2] = f2h(acc[m][nn][2]); v[3] = f2h(acc[m][nn][3]);
      *(short4v*)(hrow + (((long)(bh << 10) + nb + tok) << 7) + o0) = v;
    }
  }
  __syncthreads();
  if (t < 128)
    s1g[(bh << 10) + nb + t] = sred[0][0][t] + sred[1][0][t];
  else
    s2g[(bh << 10) + nb + (t - 128)] = sred[0][1][t - 128] + sred[1][1][t - 128];
}

// ---------------- rank + per-row threshold + sorted E/F scatter --------------
__global__ __launch_bounds__(256) void k_rank(const float* __restrict__ s1g,
                                              const float* __restrict__ s2g,
                                              float* __restrict__ sE,
                                              float* __restrict__ sF,
                                              int* __restrict__ sidx,
                                              int* __restrict__ ki,
                                              float* __restrict__ rowA,
                                              float* __restrict__ rowB,
                                              float* __restrict__ rowPd) {
  __shared__ float s2s[1024];
  __shared__ float red[4];
  const int bh = blockIdx.x, seg = blockIdx.y, t = threadIdx.x;
  f32x4 v4 = *(const f32x4*)&s2g[(bh << 10) + (t << 2)];
  *(f32x4*)&s2s[t << 2] = v4;
  __syncthreads();
  float mx = fmaxf(fmaxf(v4[0], v4[1]), fmaxf(v4[2], v4[3]));
#pragma unroll
  for (int off = 1; off < 64; off <<= 1) mx = fmaxf(mx, __shfl_xor(mx, off));
  if ((t & 63) == 0) red[t >> 6] = mx;
  __syncthreads();
  const float smax = fmaxf(fmaxf(red[0], red[1]), fmaxf(red[2], red[3]));

  const int j = (seg << 8) + t;
  const float s2j = s2s[j];
  const float s1v = s1g[(bh << 10) + j];
  const float thr = -s1v;
  int rank = 0, k = 0;
#pragma unroll 4
  for (int p4 = 0; p4 < 256; ++p4) {
    f32x4 v = *(const f32x4*)&s2s[p4 << 2];
#pragma unroll
    for (int q = 0; q < 4; ++q) {
      int p = (p4 << 2) + q;
      rank += (v[q] > s2j) || (v[q] == s2j && p < j);
      k += (v[q] > thr);
    }
  }
  const float E = __expf(s2j - smax);
  const float F = __expf(0.2f * (s2j - smax));
  const int o = (bh << 10) + rank;
  sE[o] = E; sF[o] = F; sidx[o] = j;

  float x = s1v + smax;
  float mi = fmaxf(x, 0.2f * x);  // >= row max of lrelu scores (monotone)
  float A = __expf(x - mi);
  float Bv = __expf(0.2f * x - mi);
  float xii = s1v + s2j;
  float Pd = (xii > 0.f) ? A * E : Bv * F;  // diagonal term to subtract
  const int ro = (bh << 10) + j;
  rowA[ro] = A; rowB[ro] = Bv; rowPd[ro] = Pd; ki[ro] = k;
}

// ---------------- rank rows by (k_i, i): contiguous per-chunk row ranges -----
__global__ __launch_bounds__(256) void k_rank2(const int* __restrict__ ki,
                                               int* __restrict__ rowsByK,
                                               int* __restrict__ kSorted) {
  __shared__ int ks[1024];
  const int bh = blockIdx.x, seg = blockIdx.y, t = threadIdx.x;
  *(int4v*)&ks[t << 2] = *(const int4v*)&ki[(bh << 10) + (t << 2)];
  __syncthreads();
  const int i = (seg << 8) + t;
  const int k = ks[i];
  int r = 0;
#pragma unroll 4
  for (int p4 = 0; p4 < 256; ++p4) {
    int4v v = *(const int4v*)&ks[p4 << 2];
#pragma unroll
    for (int q = 0; q < 4; ++q) {
      int p = (p4 << 2) + q;
      r += (v[q] < k) || (v[q] == k && p < i);
    }
  }
  rowsByK[(bh << 10) + r] = i;
  kSorted[(bh << 10) + r] = k;
}

// ---------------- chunk sums: PEb/PFb[bh][c][d] = sum over chunk c of E/F*h --
__global__ __launch_bounds__(256) void k_scan_a(const float* __restrict__ sE,
                                                const float* __restrict__ sF,
                                                const int* __restrict__ sidx,
                                                const short* __restrict__ hrow,
                                                float* __restrict__ PEb,
                                                float* __restrict__ PFb) {
  const int bh = blockIdx.x, cg = blockIdx.y, t = threadIdx.x;
  const int d = t & 127, half = t >> 7;
#pragma unroll
  for (int cc = 0; cc < 4; ++cc) {
    const int c = (cg << 3) + (cc << 1) + half;
    float aE = 0.f, aF = 0.f;
#pragma unroll
    for (int p16 = 0; p16 < 16; ++p16) {
      const int p = (bh << 10) + (c << 4) + p16;
      float e = sE[p], f = sF[p];
      int jj = sidx[p];
      float hv = h2f(hrow[(((bh << 10) + jj) << 7) + d]);
      aE += e * hv;
      aF += f * hv;
    }
    PEb[(bh * 65 + c) * 128 + d] = aE;
    PFb[(bh * 65 + c) * 128 + d] = aF;
  }
}

// ---------------- exclusive scan of chunk sums (in place) + scalar bounds ----
__global__ __launch_bounds__(256) void k_scan_b(float* __restrict__ PEb,
                                                float* __restrict__ PFb,
                                                const float* __restrict__ sE,
                                                const float* __restrict__ sF,
                                                float* __restrict__ cEb,
                                                float* __restrict__ cFb) {
  __shared__ float ce[64], cf[64];
  const int bh = blockIdx.x, t = threadIdx.x;
  if (t < 128) {
    const int d = t;
    float run = 0.f;
#pragma unroll 4
    for (int c = 0; c < 64; ++c) {
      int idx = (bh * 65 + c) * 128 + d;
      float tmp = PEb[idx];
      PEb[idx] = run;
      run += tmp;
    }
    PEb[(bh * 65 + 64) * 128 + d] = run;
  } else {
    const int d = t - 128;
    float run = 0.f;
#pragma unroll 4
    for (int c = 0; c < 64; ++c) {
      int idx = (bh * 65 + c) * 128 + d;
      float tmp = PFb[idx];
      PFb[idx] = run;
      run += tmp;
    }
    PFb[(bh * 65 + 64) * 128 + d] = run;
  }
  if (t < 64) {
    float se = 0.f, sf = 0.f;
#pragma unroll
    for (int p16 = 0; p16 < 16; ++p16) {
      se += sE[(bh << 10) + (t << 4) + p16];
      sf += sF[(bh << 10) + (t << 4) + p16];
    }
    ce[t] = se; cf[t] = sf;
  }
  __syncthreads();
  if (t == 0) {
    float rE = 0.f, rF = 0.f;
    for (int c = 0; c < 64; ++c) {
      float tE = ce[c], tF = cf[c];
      cEb[bh * 65 + c] = rE;
      cFb[bh * 65 + c] = rF;
      rE += tE; rF += tF;
    }
    cEb[bh * 65 + 64] = rE;
    cFb[bh * 65 + 64] = rF;
  }
}

// ---------------- per-chunk output: shared within-chunk prefixes -------------
// grid (64 bh, 64 c). Rows with k_i in chunk c are a contiguous range of the
// k-sorted row order. Chunk's 16 h-rows are read once into LDS prefix
// snapshots; each row then needs only 2 LDS reads + 1 coalesced h load.
__global__ __launch_bounds__(256) void k_chunk(const int* __restrict__ rowsByK,
                                               const int* __restrict__ kSorted,
                                               const float* __restrict__ rowA,
                                               const float* __restrict__ rowB,
                                               const float* __restrict__ rowPd,
                                               const float* __restrict__ sE,
                                               const float* __restrict__ sF,
                                               const int* __restrict__ sidx,
                                               const short* __restrict__ hrow,
                                               const float* __restrict__ PEb,
                                               const float* __restrict__ PFb,
                                               const float* __restrict__ cEb,
                                               const float* __restrict__ cFb,
                                               short* __restrict__ attn) {
  __shared__ float preE[17][128], preF[17][128];
  __shared__ float dE[17], dF[17];
  __shared__ float Echk[16], Fchk[16];
  __shared__ int Jchk[16];
  const int bh = blockIdx.x, c = blockIdx.y, t = threadIdx.x;
  const int base = bh << 10;
  // uniform binary search for this chunk's row range [rs, re)
  int rs, re;
  {
    int lo = 0, hi = 1024, tg = c << 4;
    while (lo < hi) { int mid = (lo + hi) >> 1; if (kSorted[base + mid] < tg) lo = mid + 1; else hi = mid; }
    rs = lo;
    if (c == 63) re = 1024;
    else {
      int lo2 = lo, hi2 = 1024, tg2 = (c + 1) << 4;
      while (lo2 < hi2) { int mid = (lo2 + hi2) >> 1; if (kSorted[base + mid] < tg2) lo2 = mid + 1; else hi2 = mid; }
      re = lo2;
    }
  }
  if (rs == re) return;  // uniform: all threads agree
  if (t < 16) {
    int p = base + (c << 4) + t;
    Echk[t] = sE[p]; Fchk[t] = sF[p]; Jchk[t] = sidx[p];
  }
  __syncthreads();
  const int d = t & 127, rh = t >> 7;
  if (rh == 0) {
    float run = 0.f;
    preE[0][d] = 0.f;
#pragma unroll
    for (int p = 0; p < 16; ++p) {
      run += Echk[p] * h2f(hrow[((base + Jchk[p]) << 7) + d]);
      preE[p + 1][d] = run;
    }
  } else {
    float run = 0.f;
    preF[0][d] = 0.f;
#pragma unroll
    for (int p = 0; p < 16; ++p) {
      run += Fchk[p] * h2f(hrow[((base + Jchk[p]) << 7) + d]);
      preF[p + 1][d] = run;
    }
  }
  if (t == 0) {
    float rE = 0.f, rF = 0.f;
    dE[0] = 0.f; dF[0] = 0.f;
#pragma unroll
    for (int p = 0; p < 16; ++p) {
      rE += Echk[p]; dE[p + 1] = rE;
      rF += Fchk[p]; dF[p + 1] = rF;
    }
  }
  __syncthreads();
  const float PEc = PEb[(bh * 65 + c) * 128 + d];
  const float PFc = PFb[(bh * 65 + c) * 128 + d];
  const float totFh = PFb[(bh * 65 + 64) * 128 + d];
  const float cE = cEb[bh * 65 + c], cF = cFb[bh * 65 + c];
  const float totF = cFb[bh * 65 + 64];
  const int b = bh >> 2, head = bh & 3;
#pragma unroll 1
  for (int r = rs + rh; r < re; r += 2) {
    int i = rowsByK[base + r];
    int k = kSorted[base + r];
    int kin = k - (c << 4);
    float A = rowA[base + i], Bv = rowB[base + i], Pd = rowPd[base + i];
    float num = A * (PEc + preE[kin][d]) + Bv * (totFh - PFc - preF[kin][d]);
    float den = A * (cE + dE[kin]) + Bv * (totF - cF - dF[kin]);
    float hvi = h2f(hrow[((base + i) << 7) + d]);
    num -= Pd * hvi;
    den -= Pd;
    attn[(((long)((b << 10) + i)) << 9) + (head << 7) + d] = f2h(num / den);
  }
}

// ---------------- out-proj + bias (+residual from xh) + LN (+relu) ----------
template <int HAS_RES, int DO_RELU, int WRITE_OUT>
__global__ __launch_bounds__(256) void k_outproj(const short* __restrict__ attn,
                                                 const short* __restrict__ WoT,
                                                 const float* __restrict__ bo,
                                                 const float* __restrict__ gamma,
                                                 const float* __restrict__ beta,
                                                 short* __restrict__ xh,
                                                 float* __restrict__ outp) {
  __shared__ __align__(16) short As[32 * LDP];
  __shared__ __align__(16) short Bs[128 * LDP];
  __shared__ float sredS[2][32], sredQ[2][32];
  const int t = threadIdx.x;
  const int bn0 = blockIdx.x << 5;
  const int w = t >> 6, lane = t & 63, lr = lane & 15, lq = lane >> 4;
  const int wm = w & 1, wn = w >> 1;
  f32x4 acc[4] = {};
  const int rowA_ = t >> 3, chA = (t & 7) << 3;
  const int rowB_ = t >> 1, chB = (t & 1) << 5;
  for (int k0 = 0; k0 < 512; k0 += 64) {
    {
      const short* sa = attn + ((long)(bn0 + rowA_) << 9) + k0 + chA;
      *(short8*)(As + rowA_ * LDP + chA) = *(const short8*)(sa);
      const short* sb = WoT + (rowB_ << 9) + k0 + chB;
      short* db = Bs + rowB_ * LDP + chB;
      *(short8*)(db) = *(const short8*)(sb);
      *(short8*)(db + 8) = *(const short8*)(sb + 8);
      *(short8*)(db + 16) = *(const short8*)(sb + 16);
      *(short8*)(db + 24) = *(const short8*)(sb + 24);
    }
    __syncthreads();
#pragma unroll
    for (int kk = 0; kk < 2; ++kk) {
      f16x8 a = *(const f16x8*)(As + ((wm << 4) + lr) * LDP + (kk << 5) + (lq << 3));
#pragma unroll
      for (int nn = 0; nn < 4; ++nn) {
        f16x8 b = *(const f16x8*)(Bs + ((wn << 6) + (nn << 4) + lr) * LDP + (kk << 5) + (lq << 3));
        acc[nn] = __builtin_amdgcn_mfma_f32_16x16x32_f16(a, b, acc[nn], 0, 0, 0);
      }
    }
    __syncthreads();
  }
  float v[4][4], gam[4], bet[4];
#pragma unroll
  for (int nn = 0; nn < 4; ++nn) {
    int d = (wn << 6) + (nn << 4) + lr;
    float bv = bo[d];
    gam[nn] = gamma[d];
    bet[nn] = beta[d];
#pragma unroll
    for (int r = 0; r < 4; ++r) {
      float x = acc[nn][r] + bv;
      if (HAS_RES) x += h2f(xh[((bn0 + (wm << 4) + (lq << 2) + r) << 7) + d]);
      v[nn][r] = x;
    }
  }
#pragma unroll
  for (int r = 0; r < 4; ++r) {
    float s = 0.f, q = 0.f;
#pragma unroll
    for (int nn = 0; nn < 4; ++nn) { s += v[nn][r]; q += v[nn][r] * v[nn][r]; }
#pragma unroll
    for (int mk = 1; mk < 16; mk <<= 1) { s += __shfl_xor(s, mk); q += __shfl_xor(q, mk); }
    if (lr == 0) {
      int row = (wm << 4) + (lq << 2) + r;
      sredS[wn][row] = s;
      sredQ[wn][row] = q;
    }
  }
  __syncthreads();
#pragma unroll
  for (int r = 0; r < 4; ++r) {
    int rloc = (wm << 4) + (lq << 2) + r;
    float S = sredS[0][rloc] + sredS[1][rloc];
    float Q = sredQ[0][rloc] + sredQ[1][rloc];
    float mean = S * 0.0078125f;
    float var = Q * 0.0078125f - mean * mean;
    float rstd = rsqrtf(var + 1e-5f);
    int row = bn0 + rloc;
#pragma unroll
    for (int nn = 0; nn < 4; ++nn) {
      int d = (wn << 6) + (nn << 4) + lr;
      float o = (v[nn][r] - mean) * rstd * gam[nn] + bet[nn];
      if (DO_RELU) o = fmaxf(o, 0.f);
      if (WRITE_OUT) outp[(row << 7) + d] = o;
      else xh[(row << 7) + d] = f2h(o);
    }
  }
}

extern "C" void kernel_launch(void* const* d_in, const int* in_sizes, int n_in,
                              void* d_out, int out_size, void* d_ws, size_t ws_size,
                              hipStream_t stream) {
  const float* nf = (const float*)d_in[0];
  const float* Wp = (const float*)d_in[1];
  const float* bp = (const float*)d_in[2];
  const float* W = (const float*)d_in[3];
  const float* a1 = (const float*)d_in[4];
  const float* a2 = (const float*)d_in[5];
  const float* Wo = (const float*)d_in[6];
  const float* bo = (const float*)d_in[7];
  const float* gamma = (const float*)d_in[8];
  const float* beta = (const float*)d_in[9];
  float* outp = (float*)d_out;

  char* ws = (char*)d_ws;
  short* xh = (short*)(ws);                        // 4 MB  [16384][128] f16
  short* hrow = (short*)(ws + (4ll << 20));        // 16 MB [64][1024][128] f16
  short* attn = (short*)(ws + (20ll << 20));       // 16 MB [16384][512] f16
  char* aux = ws + (36ll << 20);
  float* s1g = (float*)(aux);                      // 256 KB
  float* s2g = (float*)(aux + (256ll << 10));      // 256 KB
  float* sE = (float*)(aux + (512ll << 10));       // 256 KB sorted E
  float* sF = (float*)(aux + (768ll << 10));       // 256 KB sorted F
  int* sidx = (int*)(aux + (1024ll << 10));        // 256 KB sorted->orig idx
  int* ki = (int*)(aux + (1280ll << 10));          // 256 KB per-row threshold
  float* rowA = (float*)(aux + (1536ll << 10));    // 256 KB
  float* rowB = (float*)(aux + (1792ll << 10));    // 256 KB
  float* rowPd = (float*)(aux + (2048ll << 10));   // 256 KB
  float* cEb = (float*)(aux + (2304ll << 10));     // 17 KB (64*65 f32)
  float* cFb = (float*)(aux + (2368ll << 10));     // 17 KB
  float* PEb = (float*)(aux + (2432ll << 10));     // 2.08 MB [64][65][128]
  float* PFb = (float*)(aux + (4608ll << 10));     // 2.08 MB
  int* rowsByK = (int*)(aux + (6784ll << 10));     // 256 KB
  int* kSorted = (int*)(aux + (7040ll << 10));     // 256 KB
  short* WT = (short*)(aux + (7296ll << 10));      // 384 KB
  short* WoT = (short*)(aux + (7296ll << 10) + 393216);  // 384 KB

  k_tw<<<1536, 256, 0, stream>>>(W, Wo, WT, WoT);
  k_inproj<<<8192, 256, 0, stream>>>(nf, Wp, bp, xh);
  for (int l = 0; l < 3; ++l) {
    k_gemm_h<<<dim3(128, 4), 256, 0, stream>>>(xh, WT + l * 65536, hrow,
                                               a1 + l * 512, a2 + l * 512, s1g, s2g);
    k_rank<<<dim3(64, 4), 256, 0, stream>>>(s1g, s2g, sE, sF, sidx, ki,
                                            rowA, rowB, rowPd);
    k_rank2<<<dim3(64, 4), 256, 0, stream>>>(ki, rowsByK, kSorted);
    k_scan_a<<<dim3(64, 8), 256, 0, stream>>>(sE, sF, sidx, hrow, PEb, PFb);
    k_scan_b<<<64, 256, 0, stream>>>(PEb, PFb, sE, sF, cEb, cFb);
    k_chunk<<<dim3(64, 64), 256, 0, stream>>>(rowsByK, kSorted, rowA, rowB, rowPd,
                                              sE, sF, sidx, hrow, PEb, PFb,
                                              cEb, cFb, attn);
    if (l == 0)
      k_outproj<0, 1, 0><<<512, 256, 0, stream>>>(attn, WoT + l * 65536, bo + l * 128,
                                                  gamma + l * 128, beta + l * 128, xh, outp);
    else if (l == 1)
      k_outproj<1, 1, 0><<<512, 256, 0, stream>>>(attn, WoT + l * 65536, bo + l * 128,
                                                  gamma + l * 128, beta + l * 128, xh, outp);
    else
      k_outproj<1, 0, 1><<<512, 256, 0, stream>>>(attn, WoT + l * 65536, bo + l * 128,
                                                  gamma + l * 128, beta + l * 128, xh, outp);
  }
}

// Round 11
// 373.504 us; speedup vs baseline: 1.9078x; 1.7503x over previous
//
#include <hip/hip_runtime.h>
#include <hip/hip_bf16.h>

typedef __attribute__((ext_vector_type(8))) _Float16 f16x8;
typedef __attribute__((ext_vector_type(8))) short short8;
typedef __attribute__((ext_vector_type(4))) short short4v;
typedef __attribute__((ext_vector_type(4))) float f32x4;
typedef __attribute__((ext_vector_type(4))) int int4v;

#define LDP 72  // LDS row stride (shorts) for GEMM tiles

__device__ __forceinline__ short f2h(float f) {
  union { _Float16 h; short s; } u; u.h = (_Float16)f; return u.s;
}
__device__ __forceinline__ float h2f(short s) {
  union { short s; _Float16 h; } u; u.s = s; return (float)u.h;
}

// ---------------- weight transpose + f32->f16 ----------------
__global__ __launch_bounds__(256) void k_tw(const float* __restrict__ W,
                                            const float* __restrict__ Wo,
                                            short* __restrict__ WT,
                                            short* __restrict__ WoT) {
  int idx = blockIdx.x * 256 + threadIdx.x;
  if (idx < 3 * 512 * 128) {
    int l = idx >> 16, rem = idx & 65535;
    int c = rem >> 7, k = rem & 127;
    int h = c >> 7, o = c & 127;
    WT[idx] = f2h(W[(((l * 4 + h) * 128 + k) << 7) + o]);
  } else {
    int j = idx - 3 * 512 * 128;
    int l = j >> 16, rem = j & 65535;
    int d = rem >> 9, c = rem & 511;
    WoT[j] = f2h(Wo[((l * 512 + c) << 7) + d]);
  }
}

// ---------------- input projection ----------------
__global__ __launch_bounds__(256) void k_inproj(const float* __restrict__ nf,
                                                const float* __restrict__ Wp,
                                                const float* __restrict__ bp,
                                                short* __restrict__ xh) {
  int idx = blockIdx.x * 256 + threadIdx.x;
  int bn = idx >> 7, d = idx & 127;
  float acc = bp[d];
  const float* nr = nf + bn * 7;
#pragma unroll
  for (int i = 0; i < 7; ++i) acc += nr[i] * Wp[(i << 7) + d];
  xh[idx] = f2h(acc);
}

// ---------------- head projection (row layout) + fused s1/s2 ----------------
__global__ __launch_bounds__(256) void k_gemm_h(const short* __restrict__ xh,
                                                const short* __restrict__ WT,
                                                short* __restrict__ hrow,
                                                const float* __restrict__ a1,
                                                const float* __restrict__ a2,
                                                float* __restrict__ s1g,
                                                float* __restrict__ s2g) {
  __shared__ __align__(16) short As[128 * LDP];
  __shared__ __align__(16) short Bs[128 * LDP];
  __shared__ float sred[2][2][128];
  const int t = threadIdx.x;
  const int bn0 = blockIdx.x << 7;
  const int head = blockIdx.y;
  const int c0 = head << 7;
  const int w = t >> 6, lane = t & 63, lr = lane & 15, lq = lane >> 4;
  const int wr = w >> 1, wc = w & 1;
  f32x4 acc[4][4] = {};
  for (int k0 = 0; k0 < 128; k0 += 64) {
    const int row = t >> 1, half = (t & 1) << 5;
    {
      const short* sa = xh + ((bn0 + row) << 7) + k0 + half;
      short* da = As + row * LDP + half;
      *(short8*)(da) = *(const short8*)(sa);
      *(short8*)(da + 8) = *(const short8*)(sa + 8);
      *(short8*)(da + 16) = *(const short8*)(sa + 16);
      *(short8*)(da + 24) = *(const short8*)(sa + 24);
      const short* sb = WT + ((c0 + row) << 7) + k0 + half;
      short* db = Bs + row * LDP + half;
      *(short8*)(db) = *(const short8*)(sb);
      *(short8*)(db + 8) = *(const short8*)(sb + 8);
      *(short8*)(db + 16) = *(const short8*)(sb + 16);
      *(short8*)(db + 24) = *(const short8*)(sb + 24);
    }
    __syncthreads();
#pragma unroll
    for (int kk = 0; kk < 2; ++kk) {
      f16x8 aW[4], bX[4];
#pragma unroll
      for (int m = 0; m < 4; ++m)
        aW[m] = *(const f16x8*)(Bs + (wr * 64 + m * 16 + lr) * LDP + (kk << 5) + (lq << 3));
#pragma unroll
      for (int n = 0; n < 4; ++n)
        bX[n] = *(const f16x8*)(As + (wc * 64 + n * 16 + lr) * LDP + (kk << 5) + (lq << 3));
#pragma unroll
      for (int m = 0; m < 4; ++m)
#pragma unroll
        for (int n = 0; n < 4; ++n)
          acc[m][n] = __builtin_amdgcn_mfma_f32_16x16x32_f16(aW[m], bX[n], acc[m][n], 0, 0, 0);
    }
    __syncthreads();
  }
  const int b = bn0 >> 10;
  const int nb = bn0 & 1023;
  const int bh = (b << 2) + head;
  f32x4 av1[4], av2[4];
#pragma unroll
  for (int m = 0; m < 4; ++m) {
    av1[m] = *(const f32x4*)&a1[(head << 7) + wr * 64 + m * 16 + (lq << 2)];
    av2[m] = *(const f32x4*)&a2[(head << 7) + wr * 64 + m * 16 + (lq << 2)];
  }
#pragma unroll
  for (int nn = 0; nn < 4; ++nn) {
    float v1 = 0.f, v2 = 0.f;
#pragma unroll
    for (int m = 0; m < 4; ++m)
#pragma unroll
      for (int r = 0; r < 4; ++r) {
        v1 += acc[m][nn][r] * av1[m][r];
        v2 += acc[m][nn][r] * av2[m][r];
      }
    v1 += __shfl_xor(v1, 16); v1 += __shfl_xor(v1, 32);
    v2 += __shfl_xor(v2, 16); v2 += __shfl_xor(v2, 32);
    if (lq == 0) {
      int tok = wc * 64 + nn * 16 + lr;
      sred[wr][0][tok] = v1;
      sred[wr][1][tok] = v2;
    }
  }
#pragma unroll
  for (int m = 0; m < 4; ++m) {
    int o0 = wr * 64 + m * 16 + (lq << 2);
#pragma unroll
    for (int nn = 0; nn < 4; ++nn) {
      int tok = wc * 64 + nn * 16 + lr;
      short4v v;
      v[0] = f2h(acc[m][nn][0]); v[1] = f2h(acc[m][nn][1]);
      v[2] = f2h(acc[m][nn][2]); v[3] = f2h(acc[m][nn][3]);
      *(short4v*)(hrow + (((long)(bh << 10) + nb + tok) << 7) + o0) = v;
    }
  }
  __syncthreads();
  if (t < 128)
    s1g[(bh << 10) + nb + t] = sred[0][0][t] + sred[1][0][t];
  else
    s2g[(bh << 10) + nb + (t - 128)] = sred[0][1][t - 128] + sred[1][1][t - 128];
}

// ---------------- rank + per-row threshold + sorted E/F scatter --------------
__global__ __launch_bounds__(256) void k_rank(const float* __restrict__ s1g,
                                              const float* __restrict__ s2g,
                                              float* __restrict__ sE,
                                              float* __restrict__ sF,
                                              int* __restrict__ sidx,
                                              int* __restrict__ ki,
                                              float* __restrict__ rowA,
                                              float* __restrict__ rowB,
                                              float* __restrict__ rowPd) {
  __shared__ float s2s[1024];
  __shared__ float red[4];
  const int bh = blockIdx.x, seg = blockIdx.y, t = threadIdx.x;
  f32x4 v4 = *(const f32x4*)&s2g[(bh << 10) + (t << 2)];
  *(f32x4*)&s2s[t << 2] = v4;
  __syncthreads();
  float mx = fmaxf(fmaxf(v4[0], v4[1]), fmaxf(v4[2], v4[3]));
#pragma unroll
  for (int off = 1; off < 64; off <<= 1) mx = fmaxf(mx, __shfl_xor(mx, off));
  if ((t & 63) == 0) red[t >> 6] = mx;
  __syncthreads();
  const float smax = fmaxf(fmaxf(red[0], red[1]), fmaxf(red[2], red[3]));

  const int j = (seg << 8) + t;
  const float s2j = s2s[j];
  const float s1v = s1g[(bh << 10) + j];
  const float thr = -s1v;
  int rank = 0, k = 0;
#pragma unroll 4
  for (int p4 = 0; p4 < 256; ++p4) {
    f32x4 v = *(const f32x4*)&s2s[p4 << 2];
#pragma unroll
    for (int q = 0; q < 4; ++q) {
      int p = (p4 << 2) + q;
      rank += (v[q] > s2j) || (v[q] == s2j && p < j);
      k += (v[q] > thr);
    }
  }
  const float E = __expf(s2j - smax);
  const float F = __expf(0.2f * (s2j - smax));
  const int o = (bh << 10) + rank;
  sE[o] = E; sF[o] = F; sidx[o] = j;

  float x = s1v + smax;
  float mi = fmaxf(x, 0.2f * x);  // >= row max of lrelu scores (monotone)
  float A = __expf(x - mi);
  float Bv = __expf(0.2f * x - mi);
  float xii = s1v + s2j;
  float Pd = (xii > 0.f) ? A * E : Bv * F;  // diagonal term to subtract
  const int ro = (bh << 10) + j;
  rowA[ro] = A; rowB[ro] = Bv; rowPd[ro] = Pd; ki[ro] = k;
}

// ---------------- rank rows by (k_i, i): balanced sorted-row ranges ----------
__global__ __launch_bounds__(256) void k_rank2(const int* __restrict__ ki,
                                               int* __restrict__ rowsByK,
                                               int* __restrict__ kSorted) {
  __shared__ int ks[1024];
  const int bh = blockIdx.x, seg = blockIdx.y, t = threadIdx.x;
  *(int4v*)&ks[t << 2] = *(const int4v*)&ki[(bh << 10) + (t << 2)];
  __syncthreads();
  const int i = (seg << 8) + t;
  const int k = ks[i];
  int r = 0;
#pragma unroll 4
  for (int p4 = 0; p4 < 256; ++p4) {
    int4v v = *(const int4v*)&ks[p4 << 2];
#pragma unroll
    for (int q = 0; q < 4; ++q) {
      int p = (p4 << 2) + q;
      r += (v[q] < k) || (v[q] == k && p < i);
    }
  }
  rowsByK[(bh << 10) + r] = i;
  kSorted[(bh << 10) + r] = k;
}

// ---------------- chunk sums: PEb/PFb[bh][c][d] = sum over chunk c of E/F*h --
__global__ __launch_bounds__(256) void k_scan_a(const float* __restrict__ sE,
                                                const float* __restrict__ sF,
                                                const int* __restrict__ sidx,
                                                const short* __restrict__ hrow,
                                                float* __restrict__ PEb,
                                                float* __restrict__ PFb) {
  const int bh = blockIdx.x, cg = blockIdx.y, t = threadIdx.x;
  const int d = t & 127, half = t >> 7;
#pragma unroll
  for (int cc = 0; cc < 4; ++cc) {
    const int c = (cg << 3) + (cc << 1) + half;
    float aE = 0.f, aF = 0.f;
#pragma unroll
    for (int p16 = 0; p16 < 16; ++p16) {
      const int p = (bh << 10) + (c << 4) + p16;
      float e = sE[p], f = sF[p];
      int jj = sidx[p];
      float hv = h2f(hrow[(((bh << 10) + jj) << 7) + d]);
      aE += e * hv;
      aF += f * hv;
    }
    PEb[(bh * 65 + c) * 128 + d] = aE;
    PFb[(bh * 65 + c) * 128 + d] = aF;
  }
}

// ------- scan_b2: vector chunk-scan (reg-array ILP) + scalar per-position ----
// prefixes + per-row denominator reciprocal (rden). grid 64 bh, 256 thr.
__global__ __launch_bounds__(256) void k_scan_b2(float* __restrict__ PEb,
                                                 float* __restrict__ PFb,
                                                 const float* __restrict__ sE,
                                                 const float* __restrict__ sF,
                                                 const int* __restrict__ ki,
                                                 const float* __restrict__ rowA,
                                                 const float* __restrict__ rowB,
                                                 const float* __restrict__ rowPd,
                                                 float* __restrict__ rden) {
  __shared__ float ce[64], cf[64], ceS[65], cfS[65];
  __shared__ float sEpre[1025], sFpre[1025];
  const int bh = blockIdx.x, t = threadIdx.x;
  // phase A: in-place exclusive scan of 64 chunk sums per d (reg-array ILP)
  {
    float* P = (t < 128) ? PEb : PFb;
    const int d = t & 127;
    float v[64];
#pragma unroll
    for (int c = 0; c < 64; ++c) v[c] = P[(bh * 65 + c) * 128 + d];
    float run = 0.f;
#pragma unroll
    for (int c = 0; c < 64; ++c) {
      float tmp = v[c];
      P[(bh * 65 + c) * 128 + d] = run;
      run += tmp;
    }
    P[(bh * 65 + 64) * 128 + d] = run;
  }
  // phase B: scalar chunk sums -> serial 64-scan -> per-position prefixes
  if (t < 64) {
    float se = 0.f, sf = 0.f;
#pragma unroll
    for (int p = 0; p < 16; ++p) {
      se += sE[(bh << 10) + (t << 4) + p];
      sf += sF[(bh << 10) + (t << 4) + p];
    }
    ce[t] = se; cf[t] = sf;
  }
  __syncthreads();
  if (t == 0) {
    float rE = 0.f, rF = 0.f;
#pragma unroll
    for (int c = 0; c < 64; ++c) {
      ceS[c] = rE; cfS[c] = rF;
      rE += ce[c]; rF += cf[c];
    }
    ceS[64] = rE; cfS[64] = rF;
    sEpre[0] = 0.f; sFpre[0] = 0.f;
  }
  __syncthreads();
  if (t < 64) {
    float rE = ceS[t], rF = cfS[t];
#pragma unroll
    for (int p = 0; p < 16; ++p) {
      rE += sE[(bh << 10) + (t << 4) + p];
      rF += sF[(bh << 10) + (t << 4) + p];
      sEpre[(t << 4) + p + 1] = rE;
      sFpre[(t << 4) + p + 1] = rF;
    }
  }
  __syncthreads();
  // phase C: per-row denominator reciprocal
  const float totF = sFpre[1024];
#pragma unroll
  for (int q = 0; q < 4; ++q) {
    const int i = (t << 2) + q;
    const int ro = (bh << 10) + i;
    int k = ki[ro];
    float den = rowA[ro] * sEpre[k] + rowB[ro] * (totF - sFpre[k]) - rowPd[ro];
    rden[ro] = 1.f / den;
  }
}

// ---------------- chunk2: balanced sorted-row sweep, per-d private prefix ----
// grid (64 bh, 16 rg), 128 thr (thread t = d). 64 k-sorted rows per block.
// preE/preF[17][d] written & read ONLY by thread d -> no barriers in loop.
// Diag h-values prefetched 8-ahead; builds use 16 independent coalesced
// gathers (ILP-16). Chunk rebuild trigger is block-uniform (non-decr. c).
__global__ __launch_bounds__(128) void k_chunk2(const int* __restrict__ rowsByK,
                                                const int* __restrict__ kSorted,
                                                const float* __restrict__ rowA,
                                                const float* __restrict__ rowB,
                                                const float* __restrict__ rowPd,
                                                const float* __restrict__ rden,
                                                const float* __restrict__ sE,
                                                const float* __restrict__ sF,
                                                const int* __restrict__ sidx,
                                                const short* __restrict__ hrow,
                                                const float* __restrict__ PEb,
                                                const float* __restrict__ PFb,
                                                short* __restrict__ attn) {
  __shared__ float preE[17][128], preF[17][128];
  __shared__ int midx[64], mc[64], mkin[64];
  __shared__ float mA[64], mB[64], mPd[64], mRd[64];
  const int bh = blockIdx.x, rg = blockIdx.y, t = threadIdx.x;
  const int base = bh << 10;
  if (t < 64) {
    const int r = (rg << 6) + t;
    const int i = rowsByK[base + r];
    int k = kSorted[base + r];
    int c = k >> 4; if (c > 63) c = 63;
    midx[t] = i; mc[t] = c; mkin[t] = k - (c << 4);
    mA[t] = rowA[base + i]; mB[t] = rowB[base + i];
    mPd[t] = rowPd[base + i]; mRd[t] = rden[base + i];
  }
  __syncthreads();
  const int d = t;
  const float totFh = PFb[(bh * 65 + 64) * 128 + d];
  const long abase = ((long)((bh >> 2) << 19)) + ((bh & 3) << 7) + d;
  int ccur = -1;
  float PEc = 0.f, PFc = 0.f;
  float cur[8], nxt[8];
#pragma unroll
  for (int q = 0; q < 8; ++q)
    cur[q] = h2f(hrow[((long)(base + midx[q]) << 7) + d]);
#pragma unroll 1
  for (int g = 0; g < 8; ++g) {
    if (g < 7) {
#pragma unroll
      for (int q = 0; q < 8; ++q)
        nxt[q] = h2f(hrow[((long)(base + midx[((g + 1) << 3) + q]) << 7) + d]);
    }
#pragma unroll
    for (int q = 0; q < 8; ++q) {
      const int rr = (g << 3) + q;
      const int c = mc[rr];          // LDS broadcast -> uniform branch
      if (c != ccur) {               // rebuild prefix for chunk c
        ccur = c;
        PEc = PEb[(bh * 65 + c) * 128 + d];
        PFc = PFb[(bh * 65 + c) * 128 + d];
        float runE = 0.f, runF = 0.f;
        preE[0][d] = 0.f; preF[0][d] = 0.f;
#pragma unroll
        for (int p = 0; p < 16; ++p) {
          const int pos = base + (c << 4) + p;
          float hv = h2f(hrow[((long)(base + sidx[pos]) << 7) + d]);
          runE += sE[pos] * hv;
          runF += sF[pos] * hv;
          preE[p + 1][d] = runE;
          preF[p + 1][d] = runF;
        }
      }
      const int kin = mkin[rr];
      float num = mA[rr] * (PEc + preE[kin][d]) +
                  mB[rr] * (totFh - PFc - preF[kin][d]) - mPd[rr] * cur[q];
      attn[abase + ((long)midx[rr] << 9)] = f2h(num * mRd[rr]);
    }
#pragma unroll
    for (int q = 0; q < 8; ++q) cur[q] = nxt[q];
  }
}

// ---------------- out-proj + bias (+residual from xh) + LN (+relu) ----------
template <int HAS_RES, int DO_RELU, int WRITE_OUT>
__global__ __launch_bounds__(256) void k_outproj(const short* __restrict__ attn,
                                                 const short* __restrict__ WoT,
                                                 const float* __restrict__ bo,
                                                 const float* __restrict__ gamma,
                                                 const float* __restrict__ beta,
                                                 short* __restrict__ xh,
                                                 float* __restrict__ outp) {
  __shared__ __align__(16) short As[32 * LDP];
  __shared__ __align__(16) short Bs[128 * LDP];
  __shared__ float sredS[2][32], sredQ[2][32];
  const int t = threadIdx.x;
  const int bn0 = blockIdx.x << 5;
  const int w = t >> 6, lane = t & 63, lr = lane & 15, lq = lane >> 4;
  const int wm = w & 1, wn = w >> 1;
  f32x4 acc[4] = {};
  const int rowA_ = t >> 3, chA = (t & 7) << 3;
  const int rowB_ = t >> 1, chB = (t & 1) << 5;
  for (int k0 = 0; k0 < 512; k0 += 64) {
    {
      const short* sa = attn + ((long)(bn0 + rowA_) << 9) + k0 + chA;
      *(short8*)(As + rowA_ * LDP + chA) = *(const short8*)(sa);
      const short* sb = WoT + (rowB_ << 9) + k0 + chB;
      short* db = Bs + rowB_ * LDP + chB;
      *(short8*)(db) = *(const short8*)(sb);
      *(short8*)(db + 8) = *(const short8*)(sb + 8);
      *(short8*)(db + 16) = *(const short8*)(sb + 16);
      *(short8*)(db + 24) = *(const short8*)(sb + 24);
    }
    __syncthreads();
#pragma unroll
    for (int kk = 0; kk < 2; ++kk) {
      f16x8 a = *(const f16x8*)(As + ((wm << 4) + lr) * LDP + (kk << 5) + (lq << 3));
#pragma unroll
      for (int nn = 0; nn < 4; ++nn) {
        f16x8 b = *(const f16x8*)(Bs + ((wn << 6) + (nn << 4) + lr) * LDP + (kk << 5) + (lq << 3));
        acc[nn] = __builtin_amdgcn_mfma_f32_16x16x32_f16(a, b, acc[nn], 0, 0, 0);
      }
    }
    __syncthreads();
  }
  float v[4][4], gam[4], bet[4];
#pragma unroll
  for (int nn = 0; nn < 4; ++nn) {
    int d = (wn << 6) + (nn << 4) + lr;
    float bv = bo[d];
    gam[nn] = gamma[d];
    bet[nn] = beta[d];
#pragma unroll
    for (int r = 0; r < 4; ++r) {
      float x = acc[nn][r] + bv;
      if (HAS_RES) x += h2f(xh[((bn0 + (wm << 4) + (lq << 2) + r) << 7) + d]);
      v[nn][r] = x;
    }
  }
#pragma unroll
  for (int r = 0; r < 4; ++r) {
    float s = 0.f, q = 0.f;
#pragma unroll
    for (int nn = 0; nn < 4; ++nn) { s += v[nn][r]; q += v[nn][r] * v[nn][r]; }
#pragma unroll
    for (int mk = 1; mk < 16; mk <<= 1) { s += __shfl_xor(s, mk); q += __shfl_xor(q, mk); }
    if (lr == 0) {
      int row = (wm << 4) + (lq << 2) + r;
      sredS[wn][row] = s;
      sredQ[wn][row] = q;
    }
  }
  __syncthreads();
#pragma unroll
  for (int r = 0; r < 4; ++r) {
    int rloc = (wm << 4) + (lq << 2) + r;
    float S = sredS[0][rloc] + sredS[1][rloc];
    float Q = sredQ[0][rloc] + sredQ[1][rloc];
    float mean = S * 0.0078125f;
    float var = Q * 0.0078125f - mean * mean;
    float rstd = rsqrtf(var + 1e-5f);
    int row = bn0 + rloc;
#pragma unroll
    for (int nn = 0; nn < 4; ++nn) {
      int d = (wn << 6) + (nn << 4) + lr;
      float o = (v[nn][r] - mean) * rstd * gam[nn] + bet[nn];
      if (DO_RELU) o = fmaxf(o, 0.f);
      if (WRITE_OUT) outp[(row << 7) + d] = o;
      else xh[(row << 7) + d] = f2h(o);
    }
  }
}

extern "C" void kernel_launch(void* const* d_in, const int* in_sizes, int n_in,
                              void* d_out, int out_size, void* d_ws, size_t ws_size,
                              hipStream_t stream) {
  const float* nf = (const float*)d_in[0];
  const float* Wp = (const float*)d_in[1];
  const float* bp = (const float*)d_in[2];
  const float* W = (const float*)d_in[3];
  const float* a1 = (const float*)d_in[4];
  const float* a2 = (const float*)d_in[5];
  const float* Wo = (const float*)d_in[6];
  const float* bo = (const float*)d_in[7];
  const float* gamma = (const float*)d_in[8];
  const float* beta = (const float*)d_in[9];
  float* outp = (float*)d_out;

  char* ws = (char*)d_ws;
  short* xh = (short*)(ws);                        // 4 MB  [16384][128] f16
  short* hrow = (short*)(ws + (4ll << 20));        // 16 MB [64][1024][128] f16
  short* attn = (short*)(ws + (20ll << 20));       // 16 MB [16384][512] f16
  char* aux = ws + (36ll << 20);
  float* s1g = (float*)(aux);                      // 256 KB
  float* s2g = (float*)(aux + (256ll << 10));      // 256 KB
  float* sE = (float*)(aux + (512ll << 10));       // 256 KB sorted E
  float* sF = (float*)(aux + (768ll << 10));       // 256 KB sorted F
  int* sidx = (int*)(aux + (1024ll << 10));        // 256 KB sorted->orig idx
  int* ki = (int*)(aux + (1280ll << 10));          // 256 KB per-row threshold
  float* rowA = (float*)(aux + (1536ll << 10));    // 256 KB
  float* rowB = (float*)(aux + (1792ll << 10));    // 256 KB
  float* rowPd = (float*)(aux + (2048ll << 10));   // 256 KB
  float* rden = (float*)(aux + (2304ll << 10));    // 256 KB
  float* PEb = (float*)(aux + (2560ll << 10));     // 2.08 MB [64][65][128]
  float* PFb = (float*)(aux + (4736ll << 10));     // 2.08 MB
  int* rowsByK = (int*)(aux + (6912ll << 10));     // 256 KB
  int* kSorted = (int*)(aux + (7168ll << 10));     // 256 KB
  short* WT = (short*)(aux + (7424ll << 10));      // 384 KB
  short* WoT = (short*)(aux + (7424ll << 10) + 393216);  // 384 KB

  k_tw<<<1536, 256, 0, stream>>>(W, Wo, WT, WoT);
  k_inproj<<<8192, 256, 0, stream>>>(nf, Wp, bp, xh);
  for (int l = 0; l < 3; ++l) {
    k_gemm_h<<<dim3(128, 4), 256, 0, stream>>>(xh, WT + l * 65536, hrow,
                                               a1 + l * 512, a2 + l * 512, s1g, s2g);
    k_rank<<<dim3(64, 4), 256, 0, stream>>>(s1g, s2g, sE, sF, sidx, ki,
                                            rowA, rowB, rowPd);
    k_rank2<<<dim3(64, 4), 256, 0, stream>>>(ki, rowsByK, kSorted);
    k_scan_a<<<dim3(64, 8), 256, 0, stream>>>(sE, sF, sidx, hrow, PEb, PFb);
    k_scan_b2<<<64, 256, 0, stream>>>(PEb, PFb, sE, sF, ki, rowA, rowB, rowPd, rden);
    k_chunk2<<<dim3(64, 16), 128, 0, stream>>>(rowsByK, kSorted, rowA, rowB, rowPd,
                                               rden, sE, sF, sidx, hrow, PEb, PFb, attn);
    if (l == 0)
      k_outproj<0, 1, 0><<<512, 256, 0, stream>>>(attn, WoT + l * 65536, bo + l * 128,
                                                  gamma + l * 128, beta + l * 128, xh, outp);
    else if (l == 1)
      k_outproj<1, 1, 0><<<512, 256, 0, stream>>>(attn, WoT + l * 65536, bo + l * 128,
                                                  gamma + l * 128, beta + l * 128, xh, outp);
    else
      k_outproj<1, 0, 1><<<512, 256, 0, stream>>>(attn, WoT + l * 65536, bo + l * 128,
                                                  gamma + l * 128, beta + l * 128, xh, outp);
  }
}

// Round 14
// 178.375 us; speedup vs baseline: 3.9948x; 2.0939x over previous
//
#include <hip/hip_runtime.h>
#include <hip/hip_bf16.h>

typedef __attribute__((ext_vector_type(8))) _Float16 f16x8;
typedef __attribute__((ext_vector_type(2))) _Float16 f16x2;
typedef __attribute__((ext_vector_type(8))) short short8;
typedef __attribute__((ext_vector_type(4))) short short4v;
typedef __attribute__((ext_vector_type(4))) float f32x4;

#define LDP 72   // LDS row stride (shorts) for reg-staged GEMM tiles

typedef const __attribute__((address_space(1))) unsigned int* gas_ptr;
typedef __attribute__((address_space(3))) unsigned int* las_ptr;
#define GLDS16(gp, lp) \
  __builtin_amdgcn_global_load_lds((gas_ptr)(gp), (las_ptr)(lp), 16, 0, 0)

#if __has_builtin(__builtin_amdgcn_fdot2)
#define FDOT2(a, b, c) __builtin_amdgcn_fdot2((a), (b), (c), false)
#else
__device__ __forceinline__ float FDOT2(f16x2 a, f16x2 b, float c) {
  return c + (float)a[0] * (float)b[0] + (float)a[1] * (float)b[1];
}
#endif

union h8u {
  f16x8 v;
  f16x2 h[4];
};

__device__ __forceinline__ short f2h(float f) {
  union { _Float16 h; short s; } u; u.h = (_Float16)f; return u.s;
}
__device__ __forceinline__ float h2f(short s) {
  union { short s; _Float16 h; } u; u.s = s; return (float)u.h;
}

// ---------------- weight transpose + f32->f16 ----------------
__global__ __launch_bounds__(256) void k_tw(const float* __restrict__ W,
                                            const float* __restrict__ Wo,
                                            short* __restrict__ WT,
                                            short* __restrict__ WoT) {
  int idx = blockIdx.x * 256 + threadIdx.x;
  if (idx < 3 * 512 * 128) {
    int l = idx >> 16, rem = idx & 65535;
    int c = rem >> 7, k = rem & 127;
    int h = c >> 7, o = c & 127;
    WT[idx] = f2h(W[(((l * 4 + h) * 128 + k) << 7) + o]);
  } else {
    int j = idx - 3 * 512 * 128;
    int l = j >> 16, rem = j & 65535;
    int d = rem >> 9, c = rem & 511;
    WoT[j] = f2h(Wo[((l * 512 + c) << 7) + d]);
  }
}

// ---------------- input projection ----------------
__global__ __launch_bounds__(256) void k_inproj(const float* __restrict__ nf,
                                                const float* __restrict__ Wp,
                                                const float* __restrict__ bp,
                                                short* __restrict__ xh) {
  int idx = blockIdx.x * 256 + threadIdx.x;
  int bn = idx >> 7, d = idx & 127;
  float acc = bp[d];
  const float* nr = nf + bn * 7;
#pragma unroll
  for (int i = 0; i < 7; ++i) acc += nr[i] * Wp[(i << 7) + d];
  xh[idx] = f2h(acc);
}

// ---------------- head projection + fused s1/s2 ----------------
__global__ __launch_bounds__(256) void k_gemm_h(const short* __restrict__ xh,
                                                const short* __restrict__ WT,
                                                short* __restrict__ hT,
                                                const float* __restrict__ a1,
                                                const float* __restrict__ a2,
                                                float* __restrict__ s1g,
                                                float* __restrict__ s2g) {
  __shared__ __align__(16) short As[128 * LDP];
  __shared__ __align__(16) short Bs[128 * LDP];
  __shared__ float sred[2][2][128];
  const int t = threadIdx.x;
  const int bn0 = blockIdx.x << 7;
  const int head = blockIdx.y;
  const int c0 = head << 7;
  const int w = t >> 6, lane = t & 63, lr = lane & 15, lq = lane >> 4;
  const int wr = w >> 1, wc = w & 1;
  f32x4 acc[4][4] = {};
  for (int k0 = 0; k0 < 128; k0 += 64) {
    const int row = t >> 1, half = (t & 1) << 5;
    {
      const short* sa = xh + ((bn0 + row) << 7) + k0 + half;
      short* da = As + row * LDP + half;
      *(short8*)(da) = *(const short8*)(sa);
      *(short8*)(da + 8) = *(const short8*)(sa + 8);
      *(short8*)(da + 16) = *(const short8*)(sa + 16);
      *(short8*)(da + 24) = *(const short8*)(sa + 24);
      const short* sb = WT + ((c0 + row) << 7) + k0 + half;
      short* db = Bs + row * LDP + half;
      *(short8*)(db) = *(const short8*)(sb);
      *(short8*)(db + 8) = *(const short8*)(sb + 8);
      *(short8*)(db + 16) = *(const short8*)(sb + 16);
      *(short8*)(db + 24) = *(const short8*)(sb + 24);
    }
    __syncthreads();
#pragma unroll
    for (int kk = 0; kk < 2; ++kk) {
      f16x8 a[4], b[4];
#pragma unroll
      for (int m = 0; m < 4; ++m)
        a[m] = *(const f16x8*)(As + (wr * 64 + m * 16 + lr) * LDP + (kk << 5) + (lq << 3));
#pragma unroll
      for (int n = 0; n < 4; ++n)
        b[n] = *(const f16x8*)(Bs + (wc * 64 + n * 16 + lr) * LDP + (kk << 5) + (lq << 3));
#pragma unroll
      for (int m = 0; m < 4; ++m)
#pragma unroll
        for (int n = 0; n < 4; ++n)
          acc[m][n] = __builtin_amdgcn_mfma_f32_16x16x32_f16(a[m], b[n], acc[m][n], 0, 0, 0);
    }
    __syncthreads();
  }
  const int b = bn0 >> 10;
  const int nb = bn0 & 1023;
  float a1v[4], a2v[4];
#pragma unroll
  for (int n = 0; n < 4; ++n) {
    int d = wc * 64 + n * 16 + lr;
    a1v[n] = a1[(head << 7) + d];
    a2v[n] = a2[(head << 7) + d];
  }
#pragma unroll
  for (int m = 0; m < 4; ++m)
#pragma unroll
    for (int r = 0; r < 4; ++r) {
      float v1 = 0.f, v2 = 0.f;
#pragma unroll
      for (int n = 0; n < 4; ++n) {
        v1 += acc[m][n][r] * a1v[n];
        v2 += acc[m][n][r] * a2v[n];
      }
#pragma unroll
      for (int off = 1; off < 16; off <<= 1) {
        v1 += __shfl_xor(v1, off);
        v2 += __shfl_xor(v2, off);
      }
      if (lr == 0) {
        int row = wr * 64 + m * 16 + (lq << 2) + r;
        sred[wc][0][row] = v1;
        sred[wc][1][row] = v2;
      }
    }
#pragma unroll
  for (int m = 0; m < 4; ++m) {
    int nrow = nb + wr * 64 + m * 16 + (lq << 2);
#pragma unroll
    for (int n = 0; n < 4; ++n) {
      int d = wc * 64 + n * 16 + lr;
      long base = ((long)((((b << 2) + head) << 7) + d) << 10) + nrow;
      short4v v;
      v[0] = f2h(acc[m][n][0]); v[1] = f2h(acc[m][n][1]);
      v[2] = f2h(acc[m][n][2]); v[3] = f2h(acc[m][n][3]);
      *(short4v*)(hT + base) = v;
    }
  }
  __syncthreads();
  {
    const int bh_ = (b << 2) + head;
    if (t < 128)
      s1g[(bh_ << 10) + nb + t] = sred[0][0][t] + sred[1][0][t];
    else
      s2g[(bh_ << 10) + nb + (t - 128)] = sred[0][1][t - 128] + sred[1][1][t - 128];
  }
}

// ---------------- tiny: s2 -> max, E=exp(s2-max) f16, F=exp(.2(s2-max)) f16 ----
__global__ __launch_bounds__(256) void k_ef(const float* __restrict__ s2g,
                                            float* __restrict__ s2m,
                                            short* __restrict__ Eh,
                                            short* __restrict__ Fh) {
  const int bh = blockIdx.x, t = threadIdx.x;
  __shared__ float red[4];
  f32x4 v = *(const f32x4*)&s2g[(bh << 10) + (t << 2)];
  float mx = fmaxf(fmaxf(v[0], v[1]), fmaxf(v[2], v[3]));
#pragma unroll
  for (int off = 1; off < 64; off <<= 1) mx = fmaxf(mx, __shfl_xor(mx, off));
  if ((t & 63) == 0) red[t >> 6] = mx;
  __syncthreads();
  const float smax = fmaxf(fmaxf(red[0], red[1]), fmaxf(red[2], red[3]));
  if (t == 0) s2m[bh] = smax;
  short4v e, f;
#pragma unroll
  for (int q = 0; q < 4; ++q) {
    e[q] = f2h(__expf(v[q] - smax));
    f[q] = f2h(__expf(0.2f * (v[q] - smax)));
  }
  *(short4v*)&Eh[(bh << 10) + (t << 2)] = e;
  *(short4v*)&Fh[(bh << 10) + (t << 2)] = f;
}

// ---------------- attention ----------------
// grid (64 bh, 16 it) -> 1024 blocks = 4 blocks/CU (37 KB LDS), 16 waves/CU.
// 64-row i-tiles; waves split 2x2 over (rows, d): each wave m=2 rows-group x
// n=4 d-frags (halves per-wave ds_read vs round-7). 2-buffer pipeline with
// distance-1 prefetch and counted s_waitcnt vmcnt(4) (never 0 in steady
// state), raw s_barrier. Diagonal: tile it (block-uniform), kk half = wm.
__global__ __launch_bounds__(256) void k_attn(const short* __restrict__ hT,
                                              const float* __restrict__ s1,
                                              const short* __restrict__ Eh,
                                              const short* __restrict__ Fh,
                                              const float* __restrict__ s2max,
                                              short* __restrict__ attn) {
  __shared__ __align__(16) short Hs[2][128 * 64];
  __shared__ __align__(16) _Float16 Esh[1024];
  __shared__ __align__(16) _Float16 Fsh[1024];
  const int bh = blockIdx.x, it = blockIdx.y;
  const int i0 = it << 6;
  const int t = threadIdx.x;
  const int w = t >> 6, lane = t & 63, lr = lane & 15, lq = lane >> 4;
  const int wm = w & 1, wn = w >> 1;

  const short* hTb = hT + ((long)bh << 17);
  const int grow = (w << 5) + (lane >> 3);
  const int gcol = ((lane & 7) ^ (lane >> 3)) << 3;
  const short* gsrc = hTb + ((long)grow << 10) + gcol;

#define STAGE(buf, J0)                                             \
  do {                                                             \
    short* ldsb = &Hs[buf][(w << 5) << 6];                         \
    _Pragma("unroll") for (int i_ = 0; i_ < 4; ++i_)               \
        GLDS16(gsrc + ((long)(i_ << 3) << 10) + (J0),              \
               ldsb + ((i_ << 3) << 6));                           \
  } while (0)

  STAGE(0, 0);
  *(short4v*)&Esh[t << 2] = *(const short4v*)&Eh[(bh << 10) + (t << 2)];
  *(short4v*)&Fsh[t << 2] = *(const short4v*)&Fh[(bh << 10) + (t << 2)];

  const float smax = s2max[bh];
  f16x8 Ai8[2], Bi8[2], dmask[2];
  const f16x2 one2 = {(_Float16)1.f, (_Float16)1.f};
  float dsum[2] = {0.f, 0.f};
#pragma unroll
  for (int m = 0; m < 2; ++m) {
    const int rblk = (wm << 5) + (m << 4) + lr;   // row within 64-row block
    float s1v = s1[(bh << 10) + i0 + rblk];
    float x = s1v + smax;
    float mi = fmaxf(x, 0.2f * x);  // upper bound of row max (lrelu monotone)
    _Float16 A_ = (_Float16)__expf(x - mi);
    _Float16 B_ = (_Float16)__expf(0.2f * x - mi);
#pragma unroll
    for (int e = 0; e < 8; ++e) { Ai8[m][e] = A_; Bi8[m][e] = B_; }
    const int lqz = ((m << 1) + (lr >> 3)) & 3, ez = lr & 7;
#pragma unroll
    for (int e = 0; e < 8; ++e)
      dmask[m][e] = (lq == lqz && e == ez) ? (_Float16)0.f : (_Float16)1.f;
  }
  const int kkd = wm;  // wave-uniform diag k-half (diag col = row idx in blk)
  f32x4 acc[2][4] = {};
  __syncthreads();  // prologue: buf0 + E/F resident (full drain, once)

#define TILE(buf, jt, DIAG)                                                    \
  do {                                                                         \
    _Pragma("unroll") for (int kk = 0; kk < 2; ++kk) {                         \
      const int ebase = ((jt) << 6) + (kk << 5) + (lq << 3);                   \
      f16x8 ev8 = *(const f16x8*)&Esh[ebase];                                  \
      f16x8 fv8 = *(const f16x8*)&Fsh[ebase];                                  \
      f16x8 bf[4];                                                             \
      _Pragma("unroll") for (int n = 0; n < 4; ++n) {                          \
        const int r_ = (wn << 6) + (n << 4) + lr;                              \
        const int slot_ = ((kk << 2) + lq) ^ (r_ & 7);                         \
        bf[n] = *(const f16x8*)(&Hs[buf][(r_ << 6) + (slot_ << 3)]);           \
      }                                                                        \
      f16x8 af[2];                                                             \
      _Pragma("unroll") for (int m = 0; m < 2; ++m) {                          \
        f16x8 pm = __builtin_elementwise_max(Ai8[m] * ev8, Bi8[m] * fv8);      \
        if ((DIAG) && kk == kkd) pm = pm * dmask[m];                           \
        af[m] = pm;                                                            \
        h8u u_; u_.v = pm;                                                     \
        _Pragma("unroll") for (int p = 0; p < 4; ++p)                          \
            dsum[m] = FDOT2(u_.h[p], one2, dsum[m]);                           \
      }                                                                        \
      _Pragma("unroll") for (int m = 0; m < 2; ++m)                            \
        _Pragma("unroll") for (int n = 0; n < 4; ++n)                          \
            acc[m][n] = __builtin_amdgcn_mfma_f32_16x16x32_f16(                \
                af[m], bf[n], acc[m][n], 0, 0, 0);                             \
    }                                                                          \
  } while (0)

  int cur = 0;
#pragma unroll 1
  for (int jt = 0; jt < 16; ++jt) {
    if (jt < 15) {
      STAGE(cur ^ 1, (jt + 1) << 6);
      asm volatile("s_waitcnt vmcnt(4)" ::: "memory");  // tile jt's 4 done
    } else {
      asm volatile("s_waitcnt vmcnt(0)" ::: "memory");
    }
    __builtin_amdgcn_s_barrier();   // all waves: buf[cur] fully staged
    __builtin_amdgcn_s_setprio(1);
    TILE(cur, jt, jt == it);
    __builtin_amdgcn_s_setprio(0);
    __builtin_amdgcn_s_barrier();   // all waves done reading buf[cur]
    cur ^= 1;
  }

  const int b = bh >> 2, head = bh & 3;
#pragma unroll
  for (int m = 0; m < 2; ++m) {
    float s = dsum[m];
    s += __shfl_xor(s, 16);
    s += __shfl_xor(s, 32);  // all lq-replica lanes hold the row sum
    float rs = 1.f / s;
    f32x4 d4;
#pragma unroll
    for (int q = 0; q < 4; ++q)
      d4[q] = __shfl(rs, (lane & 48) | ((lq << 2) + q));
    int irow = i0 + (wm << 5) + (m << 4) + (lq << 2);
#pragma unroll
    for (int n = 0; n < 4; ++n) {
      int d = (wn << 6) + (n << 4) + lr;
      long base = ((long)((b << 10) + irow) << 9) + (head << 7) + d;
      attn[base] = f2h(acc[m][n][0] * d4[0]);
      attn[base + 512] = f2h(acc[m][n][1] * d4[1]);
      attn[base + 1024] = f2h(acc[m][n][2] * d4[2]);
      attn[base + 1536] = f2h(acc[m][n][3] * d4[3]);
    }
  }
#undef STAGE
#undef TILE
}

// ---------------- out-proj + bias (+residual) + LN (+relu) ----------------
// 32-row blocks, grid 512 (2 blocks/CU). Wave owns 16 rows x 64 cols; LN via
// cross-wave LDS partial-sum exchange.
template <int HAS_RES, int DO_RELU, int WRITE_OUT>
__global__ __launch_bounds__(256) void k_outproj(const short* __restrict__ attn,
                                                 const short* __restrict__ WoT,
                                                 const float* __restrict__ bo,
                                                 const float* __restrict__ gamma,
                                                 const float* __restrict__ beta,
                                                 float* __restrict__ xf,
                                                 short* __restrict__ xh,
                                                 float* __restrict__ outp) {
  __shared__ __align__(16) short As[32 * LDP];
  __shared__ __align__(16) short Bs[128 * LDP];
  __shared__ float sredS[2][32], sredQ[2][32];
  const int t = threadIdx.x;
  const int bn0 = blockIdx.x << 5;
  const int w = t >> 6, lane = t & 63, lr = lane & 15, lq = lane >> 4;
  const int wm = w & 1, wn = w >> 1;
  f32x4 acc[4] = {};
  const int rowA = t >> 3, chA = (t & 7) << 3;
  const int rowB = t >> 1, chB = (t & 1) << 5;
  for (int k0 = 0; k0 < 512; k0 += 64) {
    {
      const short* sa = attn + ((long)(bn0 + rowA) << 9) + k0 + chA;
      *(short8*)(As + rowA * LDP + chA) = *(const short8*)(sa);
      const short* sb = WoT + (rowB << 9) + k0 + chB;
      short* db = Bs + rowB * LDP + chB;
      *(short8*)(db) = *(const short8*)(sb);
      *(short8*)(db + 8) = *(const short8*)(sb + 8);
      *(short8*)(db + 16) = *(const short8*)(sb + 16);
      *(short8*)(db + 24) = *(const short8*)(sb + 24);
    }
    __syncthreads();
#pragma unroll
    for (int kk = 0; kk < 2; ++kk) {
      f16x8 a = *(const f16x8*)(As + ((wm << 4) + lr) * LDP + (kk << 5) + (lq << 3));
#pragma unroll
      for (int nn = 0; nn < 4; ++nn) {
        f16x8 b = *(const f16x8*)(Bs + ((wn << 6) + (nn << 4) + lr) * LDP + (kk << 5) + (lq << 3));
        acc[nn] = __builtin_amdgcn_mfma_f32_16x16x32_f16(a, b, acc[nn], 0, 0, 0);
      }
    }
    __syncthreads();
  }
  float v[4][4], gam[4], bet[4];
#pragma unroll
  for (int nn = 0; nn < 4; ++nn) {
    int d = (wn << 6) + (nn << 4) + lr;
    float bv = bo[d];
    gam[nn] = gamma[d];
    bet[nn] = beta[d];
#pragma unroll
    for (int r = 0; r < 4; ++r) {
      float x = acc[nn][r] + bv;
      if (HAS_RES) x += xf[((bn0 + (wm << 4) + (lq << 2) + r) << 7) + d];
      v[nn][r] = x;
    }
  }
#pragma unroll
  for (int r = 0; r < 4; ++r) {
    float s = 0.f, q = 0.f;
#pragma unroll
    for (int nn = 0; nn < 4; ++nn) { s += v[nn][r]; q += v[nn][r] * v[nn][r]; }
#pragma unroll
    for (int mk = 1; mk < 16; mk <<= 1) { s += __shfl_xor(s, mk); q += __shfl_xor(q, mk); }
    if (lr == 0) {
      int row = (wm << 4) + (lq << 2) + r;
      sredS[wn][row] = s;
      sredQ[wn][row] = q;
    }
  }
  __syncthreads();
#pragma unroll
  for (int r = 0; r < 4; ++r) {
    int rloc = (wm << 4) + (lq << 2) + r;
    float S = sredS[0][rloc] + sredS[1][rloc];
    float Q = sredQ[0][rloc] + sredQ[1][rloc];
    float mean = S * 0.0078125f;
    float var = Q * 0.0078125f - mean * mean;
    float rstd = rsqrtf(var + 1e-5f);
    int row = bn0 + rloc;
#pragma unroll
    for (int nn = 0; nn < 4; ++nn) {
      int d = (wn << 6) + (nn << 4) + lr;
      float o = (v[nn][r] - mean) * rstd * gam[nn] + bet[nn];
      if (DO_RELU) o = fmaxf(o, 0.f);
      if (WRITE_OUT) {
        outp[(row << 7) + d] = o;
      } else {
        xh[(row << 7) + d] = f2h(o);
        xf[(row << 7) + d] = o;
      }
    }
  }
}

extern "C" void kernel_launch(void* const* d_in, const int* in_sizes, int n_in,
                              void* d_out, int out_size, void* d_ws, size_t ws_size,
                              hipStream_t stream) {
  const float* nf = (const float*)d_in[0];
  const float* Wp = (const float*)d_in[1];
  const float* bp = (const float*)d_in[2];
  const float* W = (const float*)d_in[3];
  const float* a1 = (const float*)d_in[4];
  const float* a2 = (const float*)d_in[5];
  const float* Wo = (const float*)d_in[6];
  const float* bo = (const float*)d_in[7];
  const float* gamma = (const float*)d_in[8];
  const float* beta = (const float*)d_in[9];
  float* outp = (float*)d_out;

  char* ws = (char*)d_ws;
  short* xh = (short*)(ws);                                    // 4 MB
  float* xf = (float*)(ws + (4ll << 20));                      // 8 MB
  short* hT = (short*)(ws + (12ll << 20));                     // 16 MB
  short* attn = (short*)(ws + (28ll << 20));                   // 16 MB
  float* s1 = (float*)(ws + (44ll << 20));                     // 256 KB
  float* s2g = (float*)(ws + (44ll << 20) + (256ll << 10));    // 256 KB
  short* Eh = (short*)(ws + (44ll << 20) + (512ll << 10));     // 128 KB
  short* Fh = (short*)(ws + (44ll << 20) + (640ll << 10));     // 128 KB
  float* s2m = (float*)(ws + (44ll << 20) + (768ll << 10));    // 1 KB
  short* WT = (short*)(ws + (45ll << 20));                     // 384 KB
  short* WoT = (short*)(ws + (45ll << 20) + 393216);           // 384 KB

  k_tw<<<1536, 256, 0, stream>>>(W, Wo, WT, WoT);
  k_inproj<<<8192, 256, 0, stream>>>(nf, Wp, bp, xh);
  for (int l = 0; l < 3; ++l) {
    k_gemm_h<<<dim3(128, 4), 256, 0, stream>>>(xh, WT + l * 65536, hT,
                                               a1 + l * 512, a2 + l * 512, s1, s2g);
    k_ef<<<64, 256, 0, stream>>>(s2g, s2m, Eh, Fh);
    k_attn<<<dim3(64, 16), 256, 0, stream>>>(hT, s1, Eh, Fh, s2m, attn);
    if (l == 0)
      k_outproj<0, 1, 0><<<512, 256, 0, stream>>>(attn, WoT + l * 65536, bo + l * 128,
                                                  gamma + l * 128, beta + l * 128, xf, xh, outp);
    else if (l == 1)
      k_outproj<1, 1, 0><<<512, 256, 0, stream>>>(attn, WoT + l * 65536, bo + l * 128,
                                                  gamma + l * 128, beta + l * 128, xf, xh, outp);
    else
      k_outproj<1, 0, 1><<<512, 256, 0, stream>>>(attn, WoT + l * 65536, bo + l * 128,
                                                  gamma + l * 128, beta + l * 128, xf, xh, outp);
  }
}